// Round 5
// baseline (231.719 us; speedup 1.0000x reference)
//
#include <hip/hip_runtime.h>
#include <cstdint>
#include <cstddef>

#define NTOK 4096
#define DIMD 512
#define HIDH 2048
#define NEXP 8
#define TOPK 2
#define NSLOT (NTOK*TOPK)
#define SLACK 256
#define YROWS (NSLOT+SLACK)

#define BK 64

typedef short bf16x8_t __attribute__((ext_vector_type(8)));
typedef float f32x4_t  __attribute__((ext_vector_type(4)));

__device__ __forceinline__ unsigned short f2b(float f){
  unsigned int x = __float_as_uint(f);
  unsigned int r = (x + 0x7FFFu + ((x >> 16) & 1u)) >> 16;
  return (unsigned short)r;
}

// jax.nn.gelu default (approximate=True)
__device__ __forceinline__ float gelu_tanh(float x) {
  float z2 = 1.5957691216057308f * fmaf(0.044715f * x, x * x, x);
  return x / (1.f + __expf(-z2));
}

__device__ __forceinline__ void gl_lds16(const void* g, void* l){
  __builtin_amdgcn_global_load_lds((const __attribute__((address_space(1))) void*)g,
                                   (__attribute__((address_space(3))) void*)l, 16, 0, 0);
}

// ---------------- conversion kernels ----------------

__global__ __launch_bounds__(256) void cvt_x(const float* __restrict__ x, unsigned short* __restrict__ xb){
  int i = blockIdx.x*256 + threadIdx.x;
  if (i >= (NTOK*DIMD)/4) return;
  float4 v = ((const float4*)x)[i];
  ushort4 o; o.x=f2b(v.x); o.y=f2b(v.y); o.z=f2b(v.z); o.w=f2b(v.w);
  ((ushort4*)xb)[i] = o;
}

// src: [E][R][C] f32  ->  dst: [E][C][R] bf16   (R,C multiples of 64)
__global__ __launch_bounds__(256) void transpose_cvt(const float* __restrict__ src,
                                                     unsigned short* __restrict__ dst,
                                                     int R, int C){
  int e = blockIdx.z;
  src += (size_t)e*R*C; dst += (size_t)e*R*C;
  int c0 = blockIdx.x*64, r0 = blockIdx.y*64;
  __shared__ float t[64][65];
  int tr = threadIdx.x >> 4, tc = threadIdx.x & 15;
  #pragma unroll
  for (int i=0;i<4;i++){
    int r = tr + i*16;
    float4 v = *(const float4*)(src + (size_t)(r0 + r)*C + c0 + tc*4);
    t[r][tc*4+0]=v.x; t[r][tc*4+1]=v.y; t[r][tc*4+2]=v.z; t[r][tc*4+3]=v.w;
  }
  __syncthreads();
  #pragma unroll
  for (int i=0;i<4;i++){
    int c = tr + i*16;
    ushort4 o;
    o.x = f2b(t[tc*4+0][c]); o.y = f2b(t[tc*4+1][c]);
    o.z = f2b(t[tc*4+2][c]); o.w = f2b(t[tc*4+3][c]);
    *(ushort4*)(dst + (size_t)(c0 + c)*R + r0 + tc*4) = o;
  }
}

// ---------------- dispatch build ----------------
// meta[0..7]=counts, meta[8..15]=fill cursors, meta[16..23]=offsets

__global__ void count_k(const int* __restrict__ I, int* __restrict__ meta){
  int i = blockIdx.x*256+threadIdx.x;
  if (i < NSLOT) atomicAdd(&meta[I[i]], 1);
}
__global__ void scan_k(int* __restrict__ meta){
  if (threadIdx.x==0 && blockIdx.x==0){
    int s=0;
    for(int e=0;e<NEXP;e++){ meta[16+e]=s; s+=meta[e]; }
  }
}
__global__ void fill_k(const int* __restrict__ I, int* __restrict__ meta,
                       int* __restrict__ tokOf, int* __restrict__ rowOf){
  int i = blockIdx.x*256+threadIdx.x;
  if (i < NSLOT){
    int e = I[i];
    int pos = meta[16+e] + atomicAdd(&meta[8+e], 1);
    tokOf[pos] = i >> 1;
    rowOf[i] = pos;
  }
}

// ============ 256x256xBK64, 8-wave, 2-deep counted-vmcnt GEMM core ============
// LDS: 2 bufs x (A 256x64 + B 256x64) bf16 = 128 KiB.
// Staging (rule #21 both-sides swizzle): thread tid stages slot s=i*512+tid;
//   row = i*64 + (tid>>3), dest chunk c = tid&7 (LDS linear), source chunk
//   c ^ (row&7) = (tid&7)^((tid>>3)&7)  (constant per thread, involution).
// Read side applies the same XOR: chunk' = chunk ^ (l15&7)  -> conflict-free.

// ---------------- GEMM1: H = gelu(Xg . W1 + b1), bf16 out ----------------

__global__ __launch_bounds__(512,1) void gemm1(
    const unsigned short* __restrict__ Xb, const unsigned short* __restrict__ W1t,
    const float* __restrict__ B1, const int* __restrict__ meta,
    const int* __restrict__ tokOf, unsigned short* __restrict__ H)
{
  const int e = blockIdx.z;
  const int cnt = meta[e];
  const int row0 = blockIdx.y * 256;
  if (row0 >= cnt) return;
  const int off = meta[16+e];
  const int h0 = blockIdx.x * 256;

  extern __shared__ unsigned short sm[];   // [2][32768]

  const int tid = threadIdx.x;
  const int tr  = tid >> 3;
  const int csw = ((tid & 7) ^ (tr & 7)) << 3;   // swizzled source chunk offset (elems)

  const unsigned short* sA[4];
  const unsigned short* sB[4];
  #pragma unroll
  for (int i=0;i<4;i++){
    int slot = min(off + row0 + i*64 + tr, NSLOT-1);
    sA[i] = Xb  + (size_t)tokOf[slot]*DIMD + csw;
    sB[i] = W1t + ((size_t)e*HIDH + h0 + i*64 + tr)*DIMD + csw;
  }

  const int lane = tid & 63, wid = tid >> 6;
  const int wrM = (wid >> 2) * 128, wcN = (wid & 3) * 64;
  const int l15 = lane & 15, kg = lane >> 4;
  const int lx  = l15 & 7;
  int rowA[8], rowB[4];
  #pragma unroll
  for (int m=0;m<8;m++) rowA[m] = (wrM + m*16 + l15) * BK;
  #pragma unroll
  for (int n=0;n<4;n++) rowB[n] = (wcN + n*16 + l15) * BK;
  const int ch0 = ((kg    ) ^ lx) << 3;
  const int ch1 = ((kg + 4) ^ lx) << 3;

  f32x4_t acc[8][4];
  #pragma unroll
  for (int m=0;m<8;m++){
    #pragma unroll
    for (int n=0;n<4;n++) acc[m][n] = (f32x4_t){0.f,0.f,0.f,0.f};
  }

  auto stagef = [&](int buf, int kt){
    unsigned short* dA = sm + buf*32768 + tid*8;
    unsigned short* dB = dA + 16384;
    const int k0 = kt * BK;
    #pragma unroll
    for (int i=0;i<4;i++){
      gl_lds16(sA[i] + k0, dA + i*4096);
      gl_lds16(sB[i] + k0, dB + i*4096);
    }
  };

  auto khalf = [&](const unsigned short* SA, const unsigned short* SB, int ch){
    bf16x8_t bfr[4];
    #pragma unroll
    for (int n=0;n<4;n++) bfr[n] = *(const bf16x8_t*)&SB[rowB[n] + ch];
    #pragma unroll
    for (int m=0;m<8;m++){
      bf16x8_t afm = *(const bf16x8_t*)&SA[rowA[m] + ch];
      #pragma unroll
      for (int n=0;n<4;n++)
        acc[m][n] = __builtin_amdgcn_mfma_f32_16x16x32_bf16(afm, bfr[n], acc[m][n], 0,0,0);
    }
  };

  constexpr int NS = DIMD / BK;   // 8
  stagef(0, 0);
  for (int t = 0; t < NS; ++t){
    const int cur = t & 1;
    if (t + 1 < NS){
      stagef(cur ^ 1, t + 1);
      asm volatile("s_waitcnt vmcnt(8)" ::: "memory");
    } else {
      asm volatile("s_waitcnt vmcnt(0)" ::: "memory");
    }
    __builtin_amdgcn_s_barrier();
    __builtin_amdgcn_s_setprio(1);
    const unsigned short* SA = sm + cur*32768;
    const unsigned short* SB = SA + 16384;
    khalf(SA, SB, ch0);
    khalf(SA, SB, ch1);
    __builtin_amdgcn_s_setprio(0);
    __builtin_amdgcn_s_barrier();
  }

  const int r4 = kg * 4;
  #pragma unroll
  for (int n=0;n<4;n++){
    const int gcol = h0 + wcN + n*16 + l15;
    const float b1v = B1[(size_t)e*HIDH + gcol];
    #pragma unroll
    for (int m=0;m<8;m++){
      const int rbase = row0 + wrM + m*16 + r4;
      #pragma unroll
      for (int r=0;r<4;r++){
        const int row = rbase + r;
        if (row < cnt)
          H[(size_t)(off + row)*HIDH + gcol] = f2b(gelu_tanh(acc[m][n][r] + b1v));
      }
    }
  }
}

// ------- GEMM2 (split-K): Yp[kc] = H[:, kc-chunk] . W2[kc-chunk, :], f32 out -------

__global__ __launch_bounds__(512,1) void gemm2(
    const unsigned short* __restrict__ Hb, const unsigned short* __restrict__ W2t,
    const int* __restrict__ meta, float* __restrict__ Y, int nsplit)
{
  const int e = blockIdx.z;
  const int cnt = meta[e];
  const int row0 = blockIdx.y * 256;
  if (row0 >= cnt) return;
  const int off = meta[16+e];
  const int ncol = DIMD / 256;             // 2
  const int d0 = (blockIdx.x % ncol) * 256;
  const int kc = blockIdx.x / ncol;
  const int kchunk = HIDH / nsplit;
  const int kbase = kc * kchunk;
  const int NS = kchunk / BK;

  extern __shared__ unsigned short sm[];

  const int tid = threadIdx.x;
  const int tr  = tid >> 3;
  const int csw = ((tid & 7) ^ (tr & 7)) << 3;

  const unsigned short* sA[4];
  const unsigned short* sB[4];
  #pragma unroll
  for (int i=0;i<4;i++){
    int arow = min(off + row0 + i*64 + tr, YROWS-1);
    sA[i] = Hb  + (size_t)arow*HIDH + kbase + csw;
    sB[i] = W2t + ((size_t)e*DIMD + d0 + i*64 + tr)*HIDH + kbase + csw;
  }

  const int lane = tid & 63, wid = tid >> 6;
  const int wrM = (wid >> 2) * 128, wcN = (wid & 3) * 64;
  const int l15 = lane & 15, kg = lane >> 4;
  const int lx  = l15 & 7;
  int rowA[8], rowB[4];
  #pragma unroll
  for (int m=0;m<8;m++) rowA[m] = (wrM + m*16 + l15) * BK;
  #pragma unroll
  for (int n=0;n<4;n++) rowB[n] = (wcN + n*16 + l15) * BK;
  const int ch0 = ((kg    ) ^ lx) << 3;
  const int ch1 = ((kg + 4) ^ lx) << 3;

  f32x4_t acc[8][4];
  #pragma unroll
  for (int m=0;m<8;m++){
    #pragma unroll
    for (int n=0;n<4;n++) acc[m][n] = (f32x4_t){0.f,0.f,0.f,0.f};
  }

  auto stagef = [&](int buf, int kt){
    unsigned short* dA = sm + buf*32768 + tid*8;
    unsigned short* dB = dA + 16384;
    const int k0 = kt * BK;
    #pragma unroll
    for (int i=0;i<4;i++){
      gl_lds16(sA[i] + k0, dA + i*4096);
      gl_lds16(sB[i] + k0, dB + i*4096);
    }
  };

  auto khalf = [&](const unsigned short* SA, const unsigned short* SB, int ch){
    bf16x8_t bfr[4];
    #pragma unroll
    for (int n=0;n<4;n++) bfr[n] = *(const bf16x8_t*)&SB[rowB[n] + ch];
    #pragma unroll
    for (int m=0;m<8;m++){
      bf16x8_t afm = *(const bf16x8_t*)&SA[rowA[m] + ch];
      #pragma unroll
      for (int n=0;n<4;n++)
        acc[m][n] = __builtin_amdgcn_mfma_f32_16x16x32_bf16(afm, bfr[n], acc[m][n], 0,0,0);
    }
  };

  stagef(0, 0);
  for (int t = 0; t < NS; ++t){
    const int cur = t & 1;
    if (t + 1 < NS){
      stagef(cur ^ 1, t + 1);
      asm volatile("s_waitcnt vmcnt(8)" ::: "memory");
    } else {
      asm volatile("s_waitcnt vmcnt(0)" ::: "memory");
    }
    __builtin_amdgcn_s_barrier();
    __builtin_amdgcn_s_setprio(1);
    const unsigned short* SA = sm + cur*32768;
    const unsigned short* SB = SA + 16384;
    khalf(SA, SB, ch0);
    khalf(SA, SB, ch1);
    __builtin_amdgcn_s_setprio(0);
    __builtin_amdgcn_s_barrier();
  }

  float* Yp = Y + (size_t)kc * YROWS * DIMD;
  const int r4 = kg * 4;
  #pragma unroll
  for (int m=0;m<8;m++){
    const int rbase = row0 + wrM + m*16 + r4;
    #pragma unroll
    for (int r=0;r<4;r++){
      const int row = rbase + r;
      if (row < cnt){
        float* yp = Yp + (size_t)(off + row)*DIMD + d0 + wcN + l15;
        #pragma unroll
        for (int n=0;n<4;n++) yp[n*16] = acc[m][n][r];
      }
    }
  }
}

// ------- reduce: out[t] = sum_k P[t,k]*(sum_c Yc[row(t,k)] + b2[e]) -------

__global__ __launch_bounds__(128) void reduce_k(
    const float* __restrict__ P, const int* __restrict__ I, const int* __restrict__ rowOf,
    const float* __restrict__ Y, const float* __restrict__ B2, float* __restrict__ out,
    int nsplit)
{
  int t = blockIdx.x; int d4 = threadIdx.x;
  float4 a = make_float4(0.f,0.f,0.f,0.f);
  #pragma unroll
  for (int k=0;k<TOPK;k++){
    int i = t*TOPK + k;
    float p = P[i]; int e = I[i]; int r = rowOf[i];
    float4 b = *(const float4*)(B2 + (size_t)e*DIMD + d4*4);
    float4 y = make_float4(b.x, b.y, b.z, b.w);
    for (int c=0;c<nsplit;c++){
      float4 v = *(const float4*)(Y + (size_t)c*YROWS*DIMD + (size_t)r*DIMD + d4*4);
      y.x += v.x; y.y += v.y; y.z += v.z; y.w += v.w;
    }
    a.x = fmaf(p, y.x, a.x); a.y = fmaf(p, y.y, a.y);
    a.z = fmaf(p, y.z, a.z); a.w = fmaf(p, y.w, a.w);
  }
  *(float4*)(out + (size_t)t*DIMD + d4*4) = a;
}

// ================= fallback (round-1 f32 path, used if ws too small) =================

#define CAP (NTOK*TOPK)
#define ROWS 32
#define HC 64
#define NTHR 256
#define XS_LD 516
#define HS_LD 36

__global__ void fb_build(const int* __restrict__ idx, const float* __restrict__ probs,
                         int* __restrict__ counts, int* __restrict__ tok,
                         float* __restrict__ pr) {
    int i = blockIdx.x * blockDim.x + threadIdx.x;
    if (i >= NTOK * TOPK) return;
    int t = i / TOPK;
    int e = idx[i];
    float p = probs[i];
    int pos = atomicAdd(&counts[e], 1);
    tok[e * CAP + pos] = t;
    pr[e * CAP + pos] = p;
}

__global__ __launch_bounds__(NTHR)
void fb_moe(const float* __restrict__ X,
            const float* __restrict__ W1, const float* __restrict__ B1,
            const float* __restrict__ W2, const float* __restrict__ B2,
            const int* __restrict__ counts, const int* __restrict__ tok,
            const float* __restrict__ pr, float* __restrict__ out)
{
    const int e = blockIdx.y;
    const int cnt = counts[e];
    const int r0 = blockIdx.x * ROWS;
    if (r0 >= cnt) return;
    const int nr = min(ROWS, cnt - r0);

    extern __shared__ float smem[];
    float* Xs = smem;
    float* Hs = smem + ROWS * XS_LD;
    const int tid = threadIdx.x;

    for (int i = tid; i < ROWS * (DIMD / 4); i += NTHR) {
        int r = i >> 7;
        int c4 = i & 127;
        float4 v = make_float4(0.f, 0.f, 0.f, 0.f);
        if (r < nr) {
            int t = tok[e * CAP + r0 + r];
            v = *(const float4*)(X + (size_t)t * DIMD + c4 * 4);
        }
        *(float4*)(Xs + r * XS_LD + c4 * 4) = v;
    }
    __syncthreads();

    const int hq = tid & 15;
    const int rp = tid >> 4;
    const int wv = tid >> 6;
    const int ln = tid & 63;

    float yacc[8][8];
    #pragma unroll
    for (int r = 0; r < 8; ++r){
        #pragma unroll
        for (int c = 0; c < 8; ++c) yacc[r][c] = 0.f;
    }

    const float* w1base = W1 + (size_t)e * DIMD * HIDH;
    const float* w2base = W2 + (size_t)e * HIDH * DIMD;
    const float* b1base = B1 + e * HIDH;

    for (int h0 = 0; h0 < HIDH; h0 += HC) {
        float acc0[4] = {0.f, 0.f, 0.f, 0.f};
        float acc1[4] = {0.f, 0.f, 0.f, 0.f};
        const float* w1p = w1base + h0 + hq * 4;
        const float* xr0 = Xs + (rp * 2) * XS_LD;
        const float* xr1 = xr0 + XS_LD;
        #pragma unroll 2
        for (int d = 0; d < DIMD; d += 4) {
            float4 xa = *(const float4*)(xr0 + d);
            float4 xb = *(const float4*)(xr1 + d);
            float4 w0 = *(const float4*)(w1p + (size_t)(d + 0) * HIDH);
            float4 w1v = *(const float4*)(w1p + (size_t)(d + 1) * HIDH);
            float4 w2v = *(const float4*)(w1p + (size_t)(d + 2) * HIDH);
            float4 w3v = *(const float4*)(w1p + (size_t)(d + 3) * HIDH);
            float xav[4] = {xa.x, xa.y, xa.z, xa.w};
            float xbv[4] = {xb.x, xb.y, xb.z, xb.w};
            float4 wsv[4] = {w0, w1v, w2v, w3v};
            #pragma unroll
            for (int dd = 0; dd < 4; ++dd) {
                acc0[0] = fmaf(xav[dd], wsv[dd].x, acc0[0]);
                acc0[1] = fmaf(xav[dd], wsv[dd].y, acc0[1]);
                acc0[2] = fmaf(xav[dd], wsv[dd].z, acc0[2]);
                acc0[3] = fmaf(xav[dd], wsv[dd].w, acc0[3]);
                acc1[0] = fmaf(xbv[dd], wsv[dd].x, acc1[0]);
                acc1[1] = fmaf(xbv[dd], wsv[dd].y, acc1[1]);
                acc1[2] = fmaf(xbv[dd], wsv[dd].z, acc1[2]);
                acc1[3] = fmaf(xbv[dd], wsv[dd].w, acc1[3]);
            }
        }
        {
            float4 b1v = *(const float4*)(b1base + h0 + hq * 4);
            float bb[4] = {b1v.x, b1v.y, b1v.z, b1v.w};
            #pragma unroll
            for (int j = 0; j < 4; ++j) {
                Hs[(hq * 4 + j) * HS_LD + rp * 2]     = gelu_tanh(acc0[j] + bb[j]);
                Hs[(hq * 4 + j) * HS_LD + rp * 2 + 1] = gelu_tanh(acc1[j] + bb[j]);
            }
        }
        __syncthreads();

        const float* w2p = w2base + (size_t)h0 * DIMD;
        #pragma unroll 4
        for (int hc = 0; hc < HC; ++hc) {
            float4 wA = *(const float4*)(w2p + (size_t)hc * DIMD + ln * 4);
            float4 wB = *(const float4*)(w2p + (size_t)hc * DIMD + 256 + ln * 4);
            float4 hv0 = *(const float4*)(Hs + hc * HS_LD + wv * 8);
            float4 hv1 = *(const float4*)(Hs + hc * HS_LD + wv * 8 + 4);
            float hr[8] = {hv0.x, hv0.y, hv0.z, hv0.w, hv1.x, hv1.y, hv1.z, hv1.w};
            #pragma unroll
            for (int r = 0; r < 8; ++r) {
                yacc[r][0] = fmaf(hr[r], wA.x, yacc[r][0]);
                yacc[r][1] = fmaf(hr[r], wA.y, yacc[r][1]);
                yacc[r][2] = fmaf(hr[r], wA.z, yacc[r][2]);
                yacc[r][3] = fmaf(hr[r], wA.w, yacc[r][3]);
                yacc[r][4] = fmaf(hr[r], wB.x, yacc[r][4]);
                yacc[r][5] = fmaf(hr[r], wB.y, yacc[r][5]);
                yacc[r][6] = fmaf(hr[r], wB.z, yacc[r][6]);
                yacc[r][7] = fmaf(hr[r], wB.w, yacc[r][7]);
            }
        }
        __syncthreads();
    }

    const float* b2p = B2 + e * DIMD;
    float4 b2A = *(const float4*)(b2p + ln * 4);
    float4 b2B = *(const float4*)(b2p + 256 + ln * 4);
    float bA[4] = {b2A.x, b2A.y, b2A.z, b2A.w};
    float bB[4] = {b2B.x, b2B.y, b2B.z, b2B.w};
    #pragma unroll
    for (int r = 0; r < 8; ++r) {
        int rg = wv * 8 + r;
        if (rg < nr) {
            int t = tok[e * CAP + r0 + rg];
            float p = pr[e * CAP + r0 + rg];
            float* op = out + (size_t)t * DIMD;
            #pragma unroll
            for (int j = 0; j < 4; ++j) {
                atomicAdd(op + ln * 4 + j,        p * (yacc[r][j] + bA[j]));
                atomicAdd(op + 256 + ln * 4 + j,  p * (yacc[r][4 + j] + bB[j]));
            }
        }
    }
}

// ================= launch =================

extern "C" void kernel_launch(void* const* d_in, const int* in_sizes, int n_in,
                              void* d_out, int out_size, void* d_ws, size_t ws_size,
                              hipStream_t stream) {
    const float* X  = (const float*)d_in[0];
    const float* P  = (const float*)d_in[1];
    const int*   I  = (const int*)d_in[2];
    const float* W1 = (const float*)d_in[3];
    const float* B1 = (const float*)d_in[4];
    const float* W2 = (const float*)d_in[5];
    const float* B2 = (const float*)d_in[6];
    float* out = (float*)d_out;
    char* ws = (char*)d_ws;

    // ---- fast-path workspace layout; pick largest split-K that fits ----
    int nsplit = 0;
    size_t o_meta=0, o_tok=0, o_row=0, o_xb=0, o_w1t=0, o_w2t=0, o_h=0, o_y=0;
    const int cand[3] = {4, 2, 1};
    for (int ci = 0; ci < 3; ++ci) {
        int ns = cand[ci];
        size_t cur = 0;
        auto alloc = [&](size_t b){ size_t p = cur; cur += (b + 255) & ~(size_t)255; return p; };
        size_t m_ = alloc(256);
        size_t t_ = alloc((size_t)NSLOT*4);
        size_t r_ = alloc((size_t)NSLOT*4);
        size_t x_ = alloc((size_t)NTOK*DIMD*2);
        size_t w1_ = alloc((size_t)NEXP*DIMD*HIDH*2);
        size_t w2_ = alloc((size_t)NEXP*DIMD*HIDH*2);
        size_t h_ = alloc((size_t)YROWS*HIDH*2);
        size_t y_ = alloc((size_t)ns*YROWS*DIMD*4);
        if (cur <= ws_size) {
            nsplit = ns;
            o_meta=m_; o_tok=t_; o_row=r_; o_xb=x_; o_w1t=w1_; o_w2t=w2_; o_h=h_; o_y=y_;
            break;
        }
    }

    if (nsplit > 0) {
        int* meta = (int*)(ws + o_meta);
        int* tokOf = (int*)(ws + o_tok);
        int* rowOf = (int*)(ws + o_row);
        unsigned short* Xb  = (unsigned short*)(ws + o_xb);
        unsigned short* W1t = (unsigned short*)(ws + o_w1t);
        unsigned short* W2t = (unsigned short*)(ws + o_w2t);
        unsigned short* Hb  = (unsigned short*)(ws + o_h);
        float* Yb = (float*)(ws + o_y);

        hipMemsetAsync(meta, 0, 256, stream);
        cvt_x<<<(NTOK*DIMD/4 + 255)/256, 256, 0, stream>>>(X, Xb);
        transpose_cvt<<<dim3(HIDH/64, DIMD/64, NEXP), 256, 0, stream>>>(W1, W1t, DIMD, HIDH);
        transpose_cvt<<<dim3(DIMD/64, HIDH/64, NEXP), 256, 0, stream>>>(W2, W2t, HIDH, DIMD);
        count_k<<<NSLOT/256, 256, 0, stream>>>(I, meta);
        scan_k<<<1, 64, 0, stream>>>(meta);
        fill_k<<<NSLOT/256, 256, 0, stream>>>(I, meta, tokOf, rowOf);

        hipFuncSetAttribute((const void*)gemm1,
                            hipFuncAttributeMaxDynamicSharedMemorySize, 131072);
        hipFuncSetAttribute((const void*)gemm2,
                            hipFuncAttributeMaxDynamicSharedMemorySize, 131072);
        gemm1<<<dim3(HIDH/256, NSLOT/256, NEXP), 512, 131072, stream>>>(
            Xb, W1t, B1, meta, tokOf, Hb);
        gemm2<<<dim3((DIMD/256)*nsplit, NSLOT/256, NEXP), 512, 131072, stream>>>(
            Hb, W2t, meta, Yb, nsplit);
        reduce_k<<<NTOK, 128, 0, stream>>>(P, I, rowOf, Yb, B2, out, nsplit);
    } else {
        // fallback: round-1 f32 path
        int*   counts = (int*)ws;
        int*   tok    = (int*)(ws + 64);
        float* pr     = (float*)(ws + 64 + (size_t)NEXP * CAP * sizeof(int));

        hipMemsetAsync(counts, 0, NEXP * sizeof(int), stream);
        hipMemsetAsync(d_out, 0, (size_t)out_size * sizeof(float), stream);
        fb_build<<<(NTOK * TOPK + 255) / 256, 256, 0, stream>>>(I, P, counts, tok, pr);
        size_t smem = (size_t)(ROWS * XS_LD + HC * HS_LD) * sizeof(float);
        hipFuncSetAttribute((const void*)fb_moe,
                            hipFuncAttributeMaxDynamicSharedMemorySize, (int)smem);
        fb_moe<<<dim3(CAP / ROWS, NEXP), NTHR, smem, stream>>>(
            X, W1, B1, W2, B2, counts, tok, pr, out);
    }
}

// Round 6
// 203.493 us; speedup vs baseline: 1.1387x; 1.1387x over previous
//
#include <hip/hip_runtime.h>
#include <cstdint>
#include <cstddef>

#define NTOK 4096
#define DIMD 512
#define HIDH 2048
#define NEXP 8
#define TOPK 2
#define NSLOT (NTOK*TOPK)
#define SLACK 256
#define YROWS (NSLOT+SLACK)

#define BK2 64   // K-step for the 2-phase GEMM core

typedef short bf16x8_t __attribute__((ext_vector_type(8)));
typedef float f32x4_t  __attribute__((ext_vector_type(4)));

__device__ __forceinline__ unsigned short f2b(float f){
  unsigned int x = __float_as_uint(f);
  unsigned int r = (x + 0x7FFFu + ((x >> 16) & 1u)) >> 16;
  return (unsigned short)r;
}

// jax.nn.gelu default (approximate=True)
__device__ __forceinline__ float gelu_tanh(float x) {
  float z2 = 1.5957691216057308f * fmaf(0.044715f * x, x * x, x);
  return x / (1.f + __expf(-z2));
}

__device__ __forceinline__ void gl_lds16(const void* g, void* l){
  __builtin_amdgcn_global_load_lds((const __attribute__((address_space(1))) void*)g,
                                   (__attribute__((address_space(3))) void*)l, 16, 0, 0);
}

// ---------------- conversion kernels ----------------

__global__ __launch_bounds__(256) void cvt_x(const float* __restrict__ x, unsigned short* __restrict__ xb){
  int i = blockIdx.x*256 + threadIdx.x;
  if (i >= (NTOK*DIMD)/4) return;
  float4 v = ((const float4*)x)[i];
  ushort4 o; o.x=f2b(v.x); o.y=f2b(v.y); o.z=f2b(v.z); o.w=f2b(v.w);
  ((ushort4*)xb)[i] = o;
}

// src: [E][R][C] f32  ->  dst: [E][C][R] bf16   (R,C multiples of 64)
__global__ __launch_bounds__(256) void transpose_cvt(const float* __restrict__ src,
                                                     unsigned short* __restrict__ dst,
                                                     int R, int C){
  int e = blockIdx.z;
  src += (size_t)e*R*C; dst += (size_t)e*R*C;
  int c0 = blockIdx.x*64, r0 = blockIdx.y*64;
  __shared__ float t[64][65];
  int tr = threadIdx.x >> 4, tc = threadIdx.x & 15;
  #pragma unroll
  for (int i=0;i<4;i++){
    int r = tr + i*16;
    float4 v = *(const float4*)(src + (size_t)(r0 + r)*C + c0 + tc*4);
    t[r][tc*4+0]=v.x; t[r][tc*4+1]=v.y; t[r][tc*4+2]=v.z; t[r][tc*4+3]=v.w;
  }
  __syncthreads();
  #pragma unroll
  for (int i=0;i<4;i++){
    int c = tr + i*16;
    ushort4 o;
    o.x = f2b(t[tc*4+0][c]); o.y = f2b(t[tc*4+1][c]);
    o.z = f2b(t[tc*4+2][c]); o.w = f2b(t[tc*4+3][c]);
    *(ushort4*)(dst + (size_t)(c0 + c)*R + r0 + tc*4) = o;
  }
}

// ---------------- dispatch build ----------------
// meta[0..7]=counts, meta[8..15]=fill cursors, meta[16..23]=offsets

__global__ void count_k(const int* __restrict__ I, int* __restrict__ meta){
  int i = blockIdx.x*256+threadIdx.x;
  if (i < NSLOT) atomicAdd(&meta[I[i]], 1);
}
__global__ void scan_k(int* __restrict__ meta){
  if (threadIdx.x==0 && blockIdx.x==0){
    int s=0;
    for(int e=0;e<NEXP;e++){ meta[16+e]=s; s+=meta[e]; }
  }
}
__global__ void fill_k(const int* __restrict__ I, int* __restrict__ meta,
                       int* __restrict__ tokOf, int* __restrict__ rowOf){
  int i = blockIdx.x*256+threadIdx.x;
  if (i < NSLOT){
    int e = I[i];
    int pos = meta[16+e] + atomicAdd(&meta[8+e], 1);
    tokOf[pos] = i >> 1;
    rowOf[i] = pos;
  }
}

// ============ 128x128xBK64 2-phase GEMM core (T3 minimal recipe) ============
// Per iter: STAGE(next buf) -> compute(cur) -> ONE __syncthreads().
// The sync's implicit vmcnt(0)/lgkmcnt(0) drain happens AFTER compute, so the
// staged loads' HBM/L2 latency hides under the 32-MFMA/wave compute phase.
// LDS: 2 bufs x (A 128x64 + B 128x64) bf16 = 64 KiB -> 2 blocks/CU.
// Both-sides XOR swizzle (verified R5: conflicts=0): source chunk
// (tid&7)^((tid>>3)&7), LDS linear, read chunk (kg^(row&7)).

// ---------------- GEMM1: H = gelu(Xg . W1 + b1), bf16 out ----------------

__global__ __launch_bounds__(256,2) void gemm1(
    const unsigned short* __restrict__ Xb, const unsigned short* __restrict__ W1t,
    const float* __restrict__ B1, const int* __restrict__ meta,
    const int* __restrict__ tokOf, unsigned short* __restrict__ H)
{
  const int e = blockIdx.z;
  const int cnt = meta[e];
  const int row0 = blockIdx.y * 128;
  if (row0 >= cnt) return;
  const int off = meta[16+e];
  const int h0 = blockIdx.x * 128;

  extern __shared__ unsigned short sm[];   // [2][16384] shorts = 64 KiB

  const int tid = threadIdx.x;
  const int tr  = tid >> 3;                          // 0..31
  const int csw = ((tid & 7) ^ (tr & 7)) << 3;       // swizzled source chunk (elems)

  const unsigned short* sA[4];
  const unsigned short* sB[4];
  #pragma unroll
  for (int i=0;i<4;i++){
    int slot = min(off + row0 + i*32 + tr, NSLOT-1);
    sA[i] = Xb  + (size_t)tokOf[slot]*DIMD + csw;
    sB[i] = W1t + ((size_t)e*HIDH + h0 + i*32 + tr)*DIMD + csw;
  }

  const int lane = tid & 63, wid = tid >> 6;
  const int wr = (wid >> 1) * 64, wc = (wid & 1) * 64;
  const int l15 = lane & 15, kg = lane >> 4;
  int rowA[4], rowB[4];
  #pragma unroll
  for (int m=0;m<4;m++) rowA[m] = (wr + m*16 + l15) * BK2;
  #pragma unroll
  for (int n=0;n<4;n++) rowB[n] = (wc + n*16 + l15) * BK2;
  const int ch0 = ((kg    ) ^ (l15 & 7)) << 3;
  const int ch1 = ((kg + 4) ^ (l15 & 7)) << 3;

  f32x4_t acc[4][4];
  #pragma unroll
  for (int i=0;i<4;i++){
    #pragma unroll
    for (int j=0;j<4;j++) acc[i][j] = (f32x4_t){0.f,0.f,0.f,0.f};
  }

  auto stage = [&](int buf, int kt){
    unsigned short* d = sm + buf*16384 + tid*8;
    const int k0 = kt * BK2;
    #pragma unroll
    for (int i=0;i<4;i++){
      gl_lds16(sA[i] + k0, d + i*2048);
      gl_lds16(sB[i] + k0, d + 8192 + i*2048);
    }
  };

  auto compute = [&](int buf){
    const unsigned short* SA = sm + buf*16384;
    const unsigned short* SB = SA + 8192;
    #pragma unroll
    for (int h=0; h<2; ++h){
      const int ch = h ? ch1 : ch0;
      bf16x8_t bfr[4], af[4];
      #pragma unroll
      for (int n=0;n<4;n++) bfr[n] = *(const bf16x8_t*)&SB[rowB[n] + ch];
      #pragma unroll
      for (int m=0;m<4;m++) af[m]  = *(const bf16x8_t*)&SA[rowA[m] + ch];
      #pragma unroll
      for (int m=0;m<4;m++){
        #pragma unroll
        for (int n=0;n<4;n++)
          acc[m][n] = __builtin_amdgcn_mfma_f32_16x16x32_bf16(af[m], bfr[n], acc[m][n], 0,0,0);
      }
    }
  };

  constexpr int NS = DIMD / BK2;   // 8
  stage(0, 0);
  __syncthreads();
  for (int t = 0; t < NS; ++t){
    if (t + 1 < NS) stage((t+1) & 1, t+1);
    compute(t & 1);
    __syncthreads();
  }

  const int r4 = kg * 4;
  #pragma unroll
  for (int n=0;n<4;n++){
    const int gcol = h0 + wc + n*16 + l15;
    const float b1v = B1[(size_t)e*HIDH + gcol];
    #pragma unroll
    for (int m=0;m<4;m++){
      const int rbase = row0 + wr + m*16 + r4;
      #pragma unroll
      for (int r=0;r<4;r++){
        const int row = rbase + r;
        if (row < cnt)
          H[(size_t)(off + row)*HIDH + gcol] = f2b(gelu_tanh(acc[m][n][r] + b1v));
      }
    }
  }
}

// ------- GEMM2 (split-K): Yp[kc] = H[:, kc-chunk] . W2[kc-chunk, :], f32 out -------

__global__ __launch_bounds__(256,2) void gemm2(
    const unsigned short* __restrict__ Hb, const unsigned short* __restrict__ W2t,
    const int* __restrict__ meta, float* __restrict__ Y, int nsplit)
{
  const int e = blockIdx.z;
  const int cnt = meta[e];
  const int row0 = blockIdx.y * 128;
  if (row0 >= cnt) return;
  const int off = meta[16+e];
  const int ncol = DIMD / 128;             // 4
  const int d0 = (blockIdx.x % ncol) * 128;
  const int kc = blockIdx.x / ncol;
  const int kchunk = HIDH / nsplit;
  const int kbase = kc * kchunk;
  const int NS = kchunk / BK2;

  extern __shared__ unsigned short sm[];

  const int tid = threadIdx.x;
  const int tr  = tid >> 3;
  const int csw = ((tid & 7) ^ (tr & 7)) << 3;

  const unsigned short* sA[4];
  const unsigned short* sB[4];
  #pragma unroll
  for (int i=0;i<4;i++){
    int arow = min(off + row0 + i*32 + tr, YROWS-1);
    sA[i] = Hb  + (size_t)arow*HIDH + kbase + csw;
    sB[i] = W2t + ((size_t)e*DIMD + d0 + i*32 + tr)*HIDH + kbase + csw;
  }

  const int lane = tid & 63, wid = tid >> 6;
  const int wr = (wid >> 1) * 64, wc = (wid & 1) * 64;
  const int l15 = lane & 15, kg = lane >> 4;
  int rowA[4], rowB[4];
  #pragma unroll
  for (int m=0;m<4;m++) rowA[m] = (wr + m*16 + l15) * BK2;
  #pragma unroll
  for (int n=0;n<4;n++) rowB[n] = (wc + n*16 + l15) * BK2;
  const int ch0 = ((kg    ) ^ (l15 & 7)) << 3;
  const int ch1 = ((kg + 4) ^ (l15 & 7)) << 3;

  f32x4_t acc[4][4];
  #pragma unroll
  for (int i=0;i<4;i++){
    #pragma unroll
    for (int j=0;j<4;j++) acc[i][j] = (f32x4_t){0.f,0.f,0.f,0.f};
  }

  auto stage = [&](int buf, int kt){
    unsigned short* d = sm + buf*16384 + tid*8;
    const int k0 = kt * BK2;
    #pragma unroll
    for (int i=0;i<4;i++){
      gl_lds16(sA[i] + k0, d + i*2048);
      gl_lds16(sB[i] + k0, d + 8192 + i*2048);
    }
  };

  auto compute = [&](int buf){
    const unsigned short* SA = sm + buf*16384;
    const unsigned short* SB = SA + 8192;
    #pragma unroll
    for (int h=0; h<2; ++h){
      const int ch = h ? ch1 : ch0;
      bf16x8_t bfr[4], af[4];
      #pragma unroll
      for (int n=0;n<4;n++) bfr[n] = *(const bf16x8_t*)&SB[rowB[n] + ch];
      #pragma unroll
      for (int m=0;m<4;m++) af[m]  = *(const bf16x8_t*)&SA[rowA[m] + ch];
      #pragma unroll
      for (int m=0;m<4;m++){
        #pragma unroll
        for (int n=0;n<4;n++)
          acc[m][n] = __builtin_amdgcn_mfma_f32_16x16x32_bf16(af[m], bfr[n], acc[m][n], 0,0,0);
      }
    }
  };

  stage(0, 0);
  __syncthreads();
  for (int t = 0; t < NS; ++t){
    if (t + 1 < NS) stage((t+1) & 1, t+1);
    compute(t & 1);
    __syncthreads();
  }

  float* Yp = Y + (size_t)kc * YROWS * DIMD;
  const int r4 = kg * 4;
  #pragma unroll
  for (int m=0;m<4;m++){
    const int rbase = row0 + wr + m*16 + r4;
    #pragma unroll
    for (int r=0;r<4;r++){
      const int row = rbase + r;
      if (row < cnt){
        float* yp = Yp + (size_t)(off + row)*DIMD + d0 + wc + l15;
        #pragma unroll
        for (int n=0;n<4;n++) yp[n*16] = acc[m][n][r];
      }
    }
  }
}

// ------- reduce: out[t] = sum_k P[t,k]*(sum_c Yc[row(t,k)] + b2[e]) -------

__global__ __launch_bounds__(128) void reduce_k(
    const float* __restrict__ P, const int* __restrict__ I, const int* __restrict__ rowOf,
    const float* __restrict__ Y, const float* __restrict__ B2, float* __restrict__ out,
    int nsplit)
{
  int t = blockIdx.x; int d4 = threadIdx.x;
  float4 a = make_float4(0.f,0.f,0.f,0.f);
  #pragma unroll
  for (int k=0;k<TOPK;k++){
    int i = t*TOPK + k;
    float p = P[i]; int e = I[i]; int r = rowOf[i];
    float4 b = *(const float4*)(B2 + (size_t)e*DIMD + d4*4);
    float4 y = make_float4(b.x, b.y, b.z, b.w);
    for (int c=0;c<nsplit;c++){
      float4 v = *(const float4*)(Y + (size_t)c*YROWS*DIMD + (size_t)r*DIMD + d4*4);
      y.x += v.x; y.y += v.y; y.z += v.z; y.w += v.w;
    }
    a.x = fmaf(p, y.x, a.x); a.y = fmaf(p, y.y, a.y);
    a.z = fmaf(p, y.z, a.z); a.w = fmaf(p, y.w, a.w);
  }
  *(float4*)(out + (size_t)t*DIMD + d4*4) = a;
}

// ================= fallback (round-1 f32 path, used if ws too small) =================

#define CAP (NTOK*TOPK)
#define ROWS 32
#define HC 64
#define NTHR 256
#define XS_LD 516
#define HS_LD 36

__global__ void fb_build(const int* __restrict__ idx, const float* __restrict__ probs,
                         int* __restrict__ counts, int* __restrict__ tok,
                         float* __restrict__ pr) {
    int i = blockIdx.x * blockDim.x + threadIdx.x;
    if (i >= NTOK * TOPK) return;
    int t = i / TOPK;
    int e = idx[i];
    float p = probs[i];
    int pos = atomicAdd(&counts[e], 1);
    tok[e * CAP + pos] = t;
    pr[e * CAP + pos] = p;
}

__global__ __launch_bounds__(NTHR)
void fb_moe(const float* __restrict__ X,
            const float* __restrict__ W1, const float* __restrict__ B1,
            const float* __restrict__ W2, const float* __restrict__ B2,
            const int* __restrict__ counts, const int* __restrict__ tok,
            const float* __restrict__ pr, float* __restrict__ out)
{
    const int e = blockIdx.y;
    const int cnt = counts[e];
    const int r0 = blockIdx.x * ROWS;
    if (r0 >= cnt) return;
    const int nr = min(ROWS, cnt - r0);

    extern __shared__ float smem[];
    float* Xs = smem;
    float* Hs = smem + ROWS * XS_LD;
    const int tid = threadIdx.x;

    for (int i = tid; i < ROWS * (DIMD / 4); i += NTHR) {
        int r = i >> 7;
        int c4 = i & 127;
        float4 v = make_float4(0.f, 0.f, 0.f, 0.f);
        if (r < nr) {
            int t = tok[e * CAP + r0 + r];
            v = *(const float4*)(X + (size_t)t * DIMD + c4 * 4);
        }
        *(float4*)(Xs + r * XS_LD + c4 * 4) = v;
    }
    __syncthreads();

    const int hq = tid & 15;
    const int rp = tid >> 4;
    const int wv = tid >> 6;
    const int ln = tid & 63;

    float yacc[8][8];
    #pragma unroll
    for (int r = 0; r < 8; ++r){
        #pragma unroll
        for (int c = 0; c < 8; ++c) yacc[r][c] = 0.f;
    }

    const float* w1base = W1 + (size_t)e * DIMD * HIDH;
    const float* w2base = W2 + (size_t)e * HIDH * DIMD;
    const float* b1base = B1 + e * HIDH;

    for (int h0 = 0; h0 < HIDH; h0 += HC) {
        float acc0[4] = {0.f, 0.f, 0.f, 0.f};
        float acc1[4] = {0.f, 0.f, 0.f, 0.f};
        const float* w1p = w1base + h0 + hq * 4;
        const float* xr0 = Xs + (rp * 2) * XS_LD;
        const float* xr1 = xr0 + XS_LD;
        #pragma unroll 2
        for (int d = 0; d < DIMD; d += 4) {
            float4 xa = *(const float4*)(xr0 + d);
            float4 xb = *(const float4*)(xr1 + d);
            float4 w0 = *(const float4*)(w1p + (size_t)(d + 0) * HIDH);
            float4 w1v = *(const float4*)(w1p + (size_t)(d + 1) * HIDH);
            float4 w2v = *(const float4*)(w1p + (size_t)(d + 2) * HIDH);
            float4 w3v = *(const float4*)(w1p + (size_t)(d + 3) * HIDH);
            float xav[4] = {xa.x, xa.y, xa.z, xa.w};
            float xbv[4] = {xb.x, xb.y, xb.z, xb.w};
            float4 wsv[4] = {w0, w1v, w2v, w3v};
            #pragma unroll
            for (int dd = 0; dd < 4; ++dd) {
                acc0[0] = fmaf(xav[dd], wsv[dd].x, acc0[0]);
                acc0[1] = fmaf(xav[dd], wsv[dd].y, acc0[1]);
                acc0[2] = fmaf(xav[dd], wsv[dd].z, acc0[2]);
                acc0[3] = fmaf(xav[dd], wsv[dd].w, acc0[3]);
                acc1[0] = fmaf(xbv[dd], wsv[dd].x, acc1[0]);
                acc1[1] = fmaf(xbv[dd], wsv[dd].y, acc1[1]);
                acc1[2] = fmaf(xbv[dd], wsv[dd].z, acc1[2]);
                acc1[3] = fmaf(xbv[dd], wsv[dd].w, acc1[3]);
            }
        }
        {
            float4 b1v = *(const float4*)(b1base + h0 + hq * 4);
            float bb[4] = {b1v.x, b1v.y, b1v.z, b1v.w};
            #pragma unroll
            for (int j = 0; j < 4; ++j) {
                Hs[(hq * 4 + j) * HS_LD + rp * 2]     = gelu_tanh(acc0[j] + bb[j]);
                Hs[(hq * 4 + j) * HS_LD + rp * 2 + 1] = gelu_tanh(acc1[j] + bb[j]);
            }
        }
        __syncthreads();

        const float* w2p = w2base + (size_t)h0 * DIMD;
        #pragma unroll 4
        for (int hc = 0; hc < HC; ++hc) {
            float4 wA = *(const float4*)(w2p + (size_t)hc * DIMD + ln * 4);
            float4 wB = *(const float4*)(w2p + (size_t)hc * DIMD + 256 + ln * 4);
            float4 hv0 = *(const float4*)(Hs + hc * HS_LD + wv * 8);
            float4 hv1 = *(const float4*)(Hs + hc * HS_LD + wv * 8 + 4);
            float hr[8] = {hv0.x, hv0.y, hv0.z, hv0.w, hv1.x, hv1.y, hv1.z, hv1.w};
            #pragma unroll
            for (int r = 0; r < 8; ++r) {
                yacc[r][0] = fmaf(hr[r], wA.x, yacc[r][0]);
                yacc[r][1] = fmaf(hr[r], wA.y, yacc[r][1]);
                yacc[r][2] = fmaf(hr[r], wA.z, yacc[r][2]);
                yacc[r][3] = fmaf(hr[r], wA.w, yacc[r][3]);
                yacc[r][4] = fmaf(hr[r], wB.x, yacc[r][4]);
                yacc[r][5] = fmaf(hr[r], wB.y, yacc[r][5]);
                yacc[r][6] = fmaf(hr[r], wB.z, yacc[r][6]);
                yacc[r][7] = fmaf(hr[r], wB.w, yacc[r][7]);
            }
        }
        __syncthreads();
    }

    const float* b2p = B2 + e * DIMD;
    float4 b2A = *(const float4*)(b2p + ln * 4);
    float4 b2B = *(const float4*)(b2p + 256 + ln * 4);
    float bA[4] = {b2A.x, b2A.y, b2A.z, b2A.w};
    float bB[4] = {b2B.x, b2B.y, b2B.z, b2B.w};
    #pragma unroll
    for (int r = 0; r < 8; ++r) {
        int rg = wv * 8 + r;
        if (rg < nr) {
            int t = tok[e * CAP + r0 + rg];
            float p = pr[e * CAP + r0 + rg];
            float* op = out + (size_t)t * DIMD;
            #pragma unroll
            for (int j = 0; j < 4; ++j) {
                atomicAdd(op + ln * 4 + j,        p * (yacc[r][j] + bA[j]));
                atomicAdd(op + 256 + ln * 4 + j,  p * (yacc[r][4 + j] + bB[j]));
            }
        }
    }
}

// ================= launch =================

extern "C" void kernel_launch(void* const* d_in, const int* in_sizes, int n_in,
                              void* d_out, int out_size, void* d_ws, size_t ws_size,
                              hipStream_t stream) {
    const float* X  = (const float*)d_in[0];
    const float* P  = (const float*)d_in[1];
    const int*   I  = (const int*)d_in[2];
    const float* W1 = (const float*)d_in[3];
    const float* B1 = (const float*)d_in[4];
    const float* W2 = (const float*)d_in[5];
    const float* B2 = (const float*)d_in[6];
    float* out = (float*)d_out;
    char* ws = (char*)d_ws;

    // ---- fast-path workspace layout; pick largest split-K that fits ----
    int nsplit = 0;
    size_t o_meta=0, o_tok=0, o_row=0, o_xb=0, o_w1t=0, o_w2t=0, o_h=0, o_y=0;
    const int cand[3] = {4, 2, 1};
    for (int ci = 0; ci < 3; ++ci) {
        int ns = cand[ci];
        size_t cur = 0;
        auto alloc = [&](size_t b){ size_t p = cur; cur += (b + 255) & ~(size_t)255; return p; };
        size_t m_ = alloc(256);
        size_t t_ = alloc((size_t)NSLOT*4);
        size_t r_ = alloc((size_t)NSLOT*4);
        size_t x_ = alloc((size_t)NTOK*DIMD*2);
        size_t w1_ = alloc((size_t)NEXP*DIMD*HIDH*2);
        size_t w2_ = alloc((size_t)NEXP*DIMD*HIDH*2);
        size_t h_ = alloc((size_t)YROWS*HIDH*2);
        size_t y_ = alloc((size_t)ns*YROWS*DIMD*4);
        if (cur <= ws_size) {
            nsplit = ns;
            o_meta=m_; o_tok=t_; o_row=r_; o_xb=x_; o_w1t=w1_; o_w2t=w2_; o_h=h_; o_y=y_;
            break;
        }
    }

    if (nsplit > 0) {
        int* meta = (int*)(ws + o_meta);
        int* tokOf = (int*)(ws + o_tok);
        int* rowOf = (int*)(ws + o_row);
        unsigned short* Xb  = (unsigned short*)(ws + o_xb);
        unsigned short* W1t = (unsigned short*)(ws + o_w1t);
        unsigned short* W2t = (unsigned short*)(ws + o_w2t);
        unsigned short* Hb  = (unsigned short*)(ws + o_h);
        float* Yb = (float*)(ws + o_y);

        hipMemsetAsync(meta, 0, 256, stream);
        cvt_x<<<(NTOK*DIMD/4 + 255)/256, 256, 0, stream>>>(X, Xb);
        transpose_cvt<<<dim3(HIDH/64, DIMD/64, NEXP), 256, 0, stream>>>(W1, W1t, DIMD, HIDH);
        transpose_cvt<<<dim3(DIMD/64, HIDH/64, NEXP), 256, 0, stream>>>(W2, W2t, HIDH, DIMD);
        count_k<<<NSLOT/256, 256, 0, stream>>>(I, meta);
        scan_k<<<1, 64, 0, stream>>>(meta);
        fill_k<<<NSLOT/256, 256, 0, stream>>>(I, meta, tokOf, rowOf);

        hipFuncSetAttribute((const void*)gemm1,
                            hipFuncAttributeMaxDynamicSharedMemorySize, 65536);
        hipFuncSetAttribute((const void*)gemm2,
                            hipFuncAttributeMaxDynamicSharedMemorySize, 65536);
        gemm1<<<dim3(HIDH/128, NSLOT/128, NEXP), 256, 65536, stream>>>(
            Xb, W1t, B1, meta, tokOf, Hb);
        gemm2<<<dim3((DIMD/128)*nsplit, NSLOT/128, NEXP), 256, 65536, stream>>>(
            Hb, W2t, meta, Yb, nsplit);
        reduce_k<<<NTOK, 128, 0, stream>>>(P, I, rowOf, Yb, B2, out, nsplit);
    } else {
        // fallback: round-1 f32 path
        int*   counts = (int*)ws;
        int*   tok    = (int*)(ws + 64);
        float* pr     = (float*)(ws + 64 + (size_t)NEXP * CAP * sizeof(int));

        hipMemsetAsync(counts, 0, NEXP * sizeof(int), stream);
        hipMemsetAsync(d_out, 0, (size_t)out_size * sizeof(float), stream);
        fb_build<<<(NTOK * TOPK + 255) / 256, 256, 0, stream>>>(I, P, counts, tok, pr);
        size_t smem = (size_t)(ROWS * XS_LD + HC * HS_LD) * sizeof(float);
        hipFuncSetAttribute((const void*)fb_moe,
                            hipFuncAttributeMaxDynamicSharedMemorySize, (int)smem);
        fb_moe<<<dim3(CAP / ROWS, NEXP), NTHR, smem, stream>>>(
            X, W1, B1, W2, B2, counts, tok, pr, out);
    }
}